// Round 4
// baseline (111.882 us; speedup 1.0000x reference)
//
#include <hip/hip_runtime.h>
#include <hip/hip_bf16.h>
#include <cstdint>
#include <cstddef>

#define Nn 8
#define Cc 128
#define Oo 128
#define Hh 64
#define Ww 64
#define LL (Hh * Ww)
#define KP 9

typedef __attribute__((ext_vector_type(8))) short short8;
typedef __attribute__((ext_vector_type(4))) float floatx4;
typedef __attribute__((ext_vector_type(16))) float f32x16;
typedef __attribute__((ext_vector_type(4))) int intx4;

#define SGB(m, s, i) __builtin_amdgcn_sched_group_barrier(m, s, i)

__device__ __forceinline__ unsigned short f2bf(float f) {
  unsigned int u = __float_as_uint(f);
  u += 0x7fffu + ((u >> 16) & 1u);   // round-to-nearest-even
  return (unsigned short)(u >> 16);
}

// Fused prep:
//  blocks [0, 512):    x[n][c][h][w] fp32 -> xt[n][h][w][c] bf16
//  blocks [512, 896):  w_b[o][c][3][3] fp32 -> wt2 32x32-fragment-contiguous bf16
//  blocks [896, 1024): depth -> packed 27-bit branch-mask codes per pixel
__global__ __launch_bounds__(256) void prep_all(const float* __restrict__ x,
                                                const float* __restrict__ w0,
                                                const float* __restrict__ w1,
                                                const float* __restrict__ w2,
                                                const float* __restrict__ depth,
                                                const float* __restrict__ fx,
                                                unsigned short* __restrict__ xt,
                                                unsigned short* __restrict__ wt2,
                                                unsigned int* __restrict__ codesg) {
  __shared__ float tile[Cc][Ww + 1];
  __shared__ unsigned short wl[Cc * KP];
  const int bid = blockIdx.x;
  const int t = threadIdx.x;
  if (bid < Nn * Hh) {
    const int n = bid >> 6;
    const int h = bid & 63;
    const float* src = x + (size_t)n * Cc * LL + (size_t)h * Ww;
#pragma unroll
    for (int it = 0; it < 8; ++it) {
      const int idx = t + it * 256;          // 0..2047
      const int c = idx >> 4;
      const int w4 = (idx & 15) << 2;
      const float4 v = *reinterpret_cast<const float4*>(src + (size_t)c * LL + w4);
      tile[c][w4 + 0] = v.x; tile[c][w4 + 1] = v.y;
      tile[c][w4 + 2] = v.z; tile[c][w4 + 3] = v.w;
    }
    __syncthreads();
    unsigned short* dst = xt + (size_t)((n * Hh + h) * Ww) * Cc;
#pragma unroll
    for (int it = 0; it < 4; ++it) {
      const int idx = t + it * 256;          // 0..1023
      const int w = idx >> 4;
      const int ch = (idx & 15) << 3;
      short8 v;
#pragma unroll
      for (int q = 0; q < 8; ++q)
        ((unsigned short*)&v)[q] = f2bf(tile[ch + q][w]);
      *reinterpret_cast<short8*>(dst + (size_t)w * Cc + ch) = v;
    }
  } else if (bid < Nn * Hh + 3 * Oo) {
    const int bo = bid - Nn * Hh;            // 0..383
    const int b = bo >> 7;
    const int o = bo & 127;
    const float* w = (b == 0) ? w0 : (b == 1) ? w1 : w2;
    const float* src = w + (size_t)o * Cc * KP;   // contiguous 1152 floats
#pragma unroll
    for (int it = 0; it < 5; ++it) {
      const int idx = t + it * 256;
      if (idx < Cc * KP) wl[idx] = f2bf(src[idx]);   // wl[c*9+kk]
    }
    __syncthreads();
    // wt2 record layout for 32x32x16 B fragments:
    //   rec = ((b*9 + kk)*16 + (c>>3))*128 + o, 8 bf16 per record (c&7 fastest)
#pragma unroll
    for (int it = 0; it < 5; ++it) {
      const int idx = t + it * 256;          // 0..1151 = kk*128 + c
      if (idx < Cc * KP) {
        const int kk = idx >> 7;
        const int c = idx & 127;
        wt2[(size_t)(((b * 9 + kk) * 16 + (c >> 3)) * 128 + o) * 8 + (c & 7)] =
            wl[c * KP + kk];
      }
    }
  } else {
    const int p = (bid - (Nn * Hh + 3 * Oo)) * 256 + t;   // 0..32767
    const int n = p >> 12;
    const int rem = p & 4095;
    const int h = rem >> 6;
    const int w = rem & 63;
    const float center = depth[p];
    const float grid = center / fx[n];       // PIXEL_SIZE*DILATION = 1
    const float half = 0.5f * grid;
    unsigned int packed = 0u;
#pragma unroll
    for (int kk = 0; kk < KP; ++kk) {
      const int hh = h + kk / 3 - 1;
      const int ww = w + kk % 3 - 1;
      float d = 0.0f;
      if (hh >= 0 && hh < Hh && ww >= 0 && ww < Ww) d = depth[(n << 12) + hh * Ww + ww];
      const float valid = (d != 0.0f && center != 0.0f) ? 1.0f : 0.0f;
      const float dm = d * valid;
      unsigned int cb = 0u;
      if (fabsf(dm - (center + grid)) <= half) cb |= 1u;
      float m1v = (fabsf(dm - center) <= half) ? 1.0f : 0.0f;
      m1v = m1v + 1.0f - valid;
      if (m1v > 1.0f) m1v = 1.0f;
      if (m1v > 0.5f) cb |= 2u;
      if (fabsf(dm - (center - grid)) <= half) cb |= 4u;
      packed |= cb << (3 * kk);
    }
    codesg[p] = packed;
  }
}

#define LDXC 132          // pixel stride 264 B -> 2-way bank aliasing (free)
#define HALO_COLS 66      // w in [-1, 64]
#define HALO_ROWS 4       // h in [h0-1, h0+2]

__global__ __launch_bounds__(256, 2) void conv_main(
    const unsigned short* __restrict__ xt,
    const unsigned short* __restrict__ wt2,
    const unsigned int* __restrict__ codesg,
    float* __restrict__ out) {
  __shared__ __align__(16) unsigned short Xs[HALO_ROWS * HALO_COLS * LDXC];  // 69696 B

  const int g = blockIdx.x;          // 512 blocks
  const int n = g >> 6;
  const int rem = g & 63;
  const int pb = rem >> 1;           // 0..31  -> row pair
  const int ob1 = rem & 1;           // o-half
  const int h0 = pb * 2;

  const int tid = threadIdx.x;
  const int lane = tid & 63;
  const int wave = tid >> 6;
  const int l31 = lane & 31;
  const int lg = lane >> 5;
  const int wc = wave & 1;           // o 32-slice within the block's 64
  const int ks = wave >> 1;          // K-split: 64-c chunk

  // per-lane constant part of the B record address:
  //   rec = ((b*9+kk)*16 + ks*8 + half*4 + kc*2 + lg)*128 + (ob1*64 + wc*32 + l31)
  const unsigned short* wf =
      wt2 + ((size_t)(ks * 8 + lg) * 128 + ob1 * 64 + wc * 32 + l31) * 8;

  short8 Bb[2][6];   // double-buffered B prefetch; [kc*3+b]
  short8 Aa[2][8];   // double-buffered A prefetch; [mt*2+kc]

  // KK and HF may be runtime values (rolled loop); SLOT must be a literal.
#define LOADB(SLOT, KK, HF)                                                          \
  {                                                                                  \
    const int kkq = (KK), hfq = (HF);                                                \
    _Pragma("unroll")                                                                \
    for (int kc = 0; kc < 2; ++kc)                                                   \
      _Pragma("unroll")                                                              \
      for (int b = 0; b < 3; ++b)                                                    \
        Bb[SLOT][kc * 3 + b] = *reinterpret_cast<const short8*>(                     \
            wf + (size_t)(((b * 9 + kkq) * 16 + hfq * 4 + kc * 2)) * 1024);          \
  }

#define LOADA(SLOT, KK, HF)                                                          \
  {                                                                                  \
    const int kkp = (KK), hfp = (HF);                                                \
    const int dyp = kkp / 3, dxp = kkp - dyp * 3;                                    \
    const int pof = dyp * HALO_COLS + dxp + l31;                                     \
    _Pragma("unroll")                                                                \
    for (int mt = 0; mt < 4; ++mt)                                                   \
      _Pragma("unroll")                                                              \
      for (int kc = 0; kc < 2; ++kc) {                                               \
        const int pix = (mt >> 1) * HALO_COLS + (mt & 1) * 32 + pof;                 \
        const int coff = ks * 64 + hfp * 32 + kc * 16 + lg * 8;                      \
        Aa[SLOT][mt * 2 + kc] =                                                      \
            *reinterpret_cast<const short8*>(&Xs[pix * LDXC + coff]);                \
      }                                                                              \
  }

  // 24 MFMA on (B slot BSLOT, A slot ASLOT) at kernel tap KK.
#define COMPUTE(BSLOT, ASLOT, KK)                                                    \
  {                                                                                  \
    const int shift = 3 * (KK);                                                      \
    _Pragma("unroll")                                                                \
    for (int b = 0; b < 3; ++b) {                                                    \
      int msk[4];                                                                    \
      _Pragma("unroll")                                                              \
      for (int mt = 0; mt < 4; ++mt)                                                 \
        msk[mt] = __builtin_amdgcn_sbfe((int)cd2[mt], shift + b, 1);                 \
      _Pragma("unroll")                                                              \
      for (int kc = 0; kc < 2; ++kc) {                                               \
        _Pragma("unroll")                                                            \
        for (int mt = 0; mt < 4; ++mt) {                                             \
          intx4 a4 = *reinterpret_cast<const intx4*>(&Aa[ASLOT][mt * 2 + kc]);       \
          intx4 m4 = {msk[mt], msk[mt], msk[mt], msk[mt]};                           \
          a4 &= m4;                                                                  \
          const short8 af = *reinterpret_cast<const short8*>(&a4);                   \
          acc2[mt] = __builtin_amdgcn_mfma_f32_32x32x16_bf16(                        \
              af, Bb[BSLOT][kc * 3 + b], acc2[mt], 0, 0, 0);                         \
        }                                                                            \
      }                                                                              \
    }                                                                                \
  }

  // schedule template for one COMPUTE + adjacent LOADA (8 DS) + LOADB (6 VMEM)
#define STEP_SGB                                                                     \
  SGB(0x008, 2, 0); SGB(0x100, 1, 0); SGB(0x020, 1, 0); SGB(0x002, 9, 0);            \
  SGB(0x008, 2, 0); SGB(0x100, 1, 0); SGB(0x020, 1, 0); SGB(0x002, 9, 0);            \
  SGB(0x008, 2, 0); SGB(0x100, 1, 0); SGB(0x020, 1, 0); SGB(0x002, 9, 0);            \
  SGB(0x008, 2, 0); SGB(0x100, 1, 0); SGB(0x020, 1, 0); SGB(0x002, 9, 0);            \
  SGB(0x008, 2, 0); SGB(0x100, 1, 0); SGB(0x020, 1, 0); SGB(0x002, 9, 0);            \
  SGB(0x008, 2, 0); SGB(0x100, 1, 0); SGB(0x020, 1, 0); SGB(0x002, 9, 0);            \
  SGB(0x008, 2, 0); SGB(0x100, 1, 0); SGB(0x002, 9, 0);                              \
  SGB(0x008, 2, 0); SGB(0x100, 1, 0); SGB(0x002, 9, 0);                              \
  SGB(0x008, 2, 0); SGB(0x002, 9, 0);                                                \
  SGB(0x008, 2, 0); SGB(0x002, 9, 0);                                                \
  SGB(0x008, 2, 0); SGB(0x002, 9, 0);                                                \
  SGB(0x008, 2, 0); SGB(0x002, 9, 0);

  // ---- B prologue loads FIRST: L2 latency overlaps halo staging ----
  LOADB(0, 0, 0)
  LOADB(1, 0, 1)

  // ---- branch-mask codes: lane l31 owns pixel row mt*32+l31 of the 128-pixel tile
  unsigned int cd2[4];
  {
    const unsigned int* cp = codesg + (n << 12) + h0 * 64;
#pragma unroll
    for (int mt = 0; mt < 4; ++mt) cd2[mt] = cp[mt * 32 + l31];
  }

  // ---- stage halo tile ONCE: Xs[(hrel*66 + ww+1)][c] = xt[n, h0-1+hrel, ww, c] ----
#pragma unroll
  for (int it = 0; it < 17; ++it) {
    const int idx = tid + it * 256;          // chunks of 8 channels
    if (idx < HALO_ROWS * HALO_COLS * 16) {
      const int ch = (idx & 15) << 3;
      const int pixidx = idx >> 4;           // 0..263
      const int lc = pixidx % HALO_COLS;
      const int hrel = pixidx / HALO_COLS;
      const int hh = h0 - 1 + hrel;
      const int ww = lc - 1;
      short8 v = {0, 0, 0, 0, 0, 0, 0, 0};
      if (hh >= 0 && hh < Hh && ww >= 0 && ww < Ww)
        v = *reinterpret_cast<const short8*>(
            xt + (size_t)((n * Hh + hh) * Ww + ww) * Cc + ch);
      *reinterpret_cast<short8*>(&Xs[pixidx * LDXC + ch]) = v;
    }
  }

  __syncthreads();

  f32x16 acc2[4];
#pragma unroll
  for (int mt = 0; mt < 4; ++mt)
    acc2[mt] = (f32x16){0.f, 0.f, 0.f, 0.f, 0.f, 0.f, 0.f, 0.f,
                        0.f, 0.f, 0.f, 0.f, 0.f, 0.f, 0.f, 0.f};

  LOADA(0, 0, 0)

  // ---- rolled 9-iteration K-loop, fixed 2-step double-buffered body ----
  // Invariant at body p entry: B0=B(p,0), B1=B(p,1), A0=A(p,0).
  // per half-body: 6 B VMEM + 8 A ds_reads + 24 MFMA + ~110 mask VALU.
#pragma unroll 1
  for (int p = 0; p < 8; ++p) {
    LOADA(1, p, 1)
    COMPUTE(0, 0, p)
    LOADB(0, p + 1, 0)
    STEP_SGB
    LOADA(0, p + 1, 0)
    COMPUTE(1, 1, p)
    LOADB(1, p + 1, 1)
    STEP_SGB
  }
  // tail p = 8
  LOADA(1, 8, 1)
  COMPUTE(0, 0, 8)
  COMPUTE(1, 1, 8)

  // ---- split-K reduction: ks=1 waves dump partials into LDS (Xs is dead) ----
  __syncthreads();
  float* scratch = reinterpret_cast<float*>(Xs);   // 32 KB used of 69.7 KB
  if (ks == 1) {
#pragma unroll
    for (int mt = 0; mt < 4; ++mt)
#pragma unroll
      for (int q4 = 0; q4 < 4; ++q4) {
        const floatx4 v = {acc2[mt][q4 * 4 + 0], acc2[mt][q4 * 4 + 1],
                           acc2[mt][q4 * 4 + 2], acc2[mt][q4 * 4 + 3]};
        *reinterpret_cast<floatx4*>(
            &scratch[(((wc * 4 + mt) * 4 + q4) * 64 + lane) * 4]) = v;
      }
  }
  __syncthreads();
  if (ks == 0) {
    const int o = ob1 * 64 + wc * 32 + l31;
#pragma unroll
    for (int mt = 0; mt < 4; ++mt) {
      const int h = h0 + (mt >> 1);
      const int wbase = (mt & 1) * 32;
#pragma unroll
      for (int q4 = 0; q4 < 4; ++q4) {
        const floatx4 other = *reinterpret_cast<const floatx4*>(
            &scratch[(((wc * 4 + mt) * 4 + q4) * 64 + lane) * 4]);
        const floatx4 mine = {acc2[mt][q4 * 4 + 0], acc2[mt][q4 * 4 + 1],
                              acc2[mt][q4 * 4 + 2], acc2[mt][q4 * 4 + 3]};
        const floatx4 sum = mine + other;
        const int w = wbase + q4 * 8 + lg * 4;   // row=(reg&3)+8*(reg>>2)+4*lg
        float* dst = out + (size_t)(n * Oo + o) * LL + h * Ww + w;
        *reinterpret_cast<floatx4*>(dst) = sum;
      }
    }
  }
}

extern "C" void kernel_launch(void* const* d_in, const int* in_sizes, int n_in,
                              void* d_out, int out_size, void* d_ws, size_t ws_size,
                              hipStream_t stream) {
  const float* x     = (const float*)d_in[0];
  const float* depth = (const float*)d_in[1];
  const float* fx    = (const float*)d_in[2];
  const float* w0    = (const float*)d_in[3];
  const float* w1    = (const float*)d_in[4];
  const float* w2    = (const float*)d_in[5];
  float* out = (float*)d_out;

  // ws layout: xt (8 MB) | wt2 (0.88 MB) | codes (128 KB)
  unsigned short* xt = (unsigned short*)d_ws;
  unsigned short* wt2 = xt + (size_t)Nn * Hh * Ww * Cc;
  unsigned int* codesg = (unsigned int*)(wt2 + (size_t)3 * KP * Oo * Cc);

  prep_all<<<Nn * Hh + 3 * Oo + 128, 256, 0, stream>>>(x, w0, w1, w2, depth, fx, xt, wt2, codesg);
  conv_main<<<512, 256, 0, stream>>>(xt, wt2, codesg, out);
}

// Round 5
// 110.213 us; speedup vs baseline: 1.0151x; 1.0151x over previous
//
#include <hip/hip_runtime.h>
#include <hip/hip_bf16.h>
#include <cstdint>
#include <cstddef>

#define Nn 8
#define Cc 128
#define Oo 128
#define Hh 64
#define Ww 64
#define LL (Hh * Ww)
#define KP 9

typedef __attribute__((ext_vector_type(8))) short short8;
typedef __attribute__((ext_vector_type(4))) float floatx4;
typedef __attribute__((ext_vector_type(16))) float f32x16;
typedef __attribute__((ext_vector_type(4))) int intx4;

__device__ __forceinline__ unsigned short f2bf(float f) {
  unsigned int u = __float_as_uint(f);
  u += 0x7fffu + ((u >> 16) & 1u);   // round-to-nearest-even
  return (unsigned short)(u >> 16);
}

// Fused prep:
//  blocks [0, 512):    x[n][c][h][w] fp32 -> xt[n][h][w][c] bf16
//  blocks [512, 896):  w_b[o][c][3][3] fp32 -> wt2 32x32-fragment-contiguous bf16
//  blocks [896, 1024): depth -> packed 27-bit branch-mask codes per pixel
__global__ __launch_bounds__(256) void prep_all(const float* __restrict__ x,
                                                const float* __restrict__ w0,
                                                const float* __restrict__ w1,
                                                const float* __restrict__ w2,
                                                const float* __restrict__ depth,
                                                const float* __restrict__ fx,
                                                unsigned short* __restrict__ xt,
                                                unsigned short* __restrict__ wt2,
                                                unsigned int* __restrict__ codesg) {
  __shared__ float tile[Cc][Ww + 1];
  __shared__ unsigned short wl[Cc * KP];
  const int bid = blockIdx.x;
  const int t = threadIdx.x;
  if (bid < Nn * Hh) {
    const int n = bid >> 6;
    const int h = bid & 63;
    const float* src = x + (size_t)n * Cc * LL + (size_t)h * Ww;
#pragma unroll
    for (int it = 0; it < 8; ++it) {
      const int idx = t + it * 256;          // 0..2047
      const int c = idx >> 4;
      const int w4 = (idx & 15) << 2;
      const float4 v = *reinterpret_cast<const float4*>(src + (size_t)c * LL + w4);
      tile[c][w4 + 0] = v.x; tile[c][w4 + 1] = v.y;
      tile[c][w4 + 2] = v.z; tile[c][w4 + 3] = v.w;
    }
    __syncthreads();
    unsigned short* dst = xt + (size_t)((n * Hh + h) * Ww) * Cc;
#pragma unroll
    for (int it = 0; it < 4; ++it) {
      const int idx = t + it * 256;          // 0..1023
      const int w = idx >> 4;
      const int ch = (idx & 15) << 3;
      short8 v;
#pragma unroll
      for (int q = 0; q < 8; ++q)
        ((unsigned short*)&v)[q] = f2bf(tile[ch + q][w]);
      *reinterpret_cast<short8*>(dst + (size_t)w * Cc + ch) = v;
    }
  } else if (bid < Nn * Hh + 3 * Oo) {
    const int bo = bid - Nn * Hh;            // 0..383
    const int b = bo >> 7;
    const int o = bo & 127;
    const float* w = (b == 0) ? w0 : (b == 1) ? w1 : w2;
    const float* src = w + (size_t)o * Cc * KP;   // contiguous 1152 floats
#pragma unroll
    for (int it = 0; it < 5; ++it) {
      const int idx = t + it * 256;
      if (idx < Cc * KP) wl[idx] = f2bf(src[idx]);   // wl[c*9+kk]
    }
    __syncthreads();
    // wt2 record layout for 32x32x16 B fragments:
    //   rec = ((b*9 + kk)*16 + (c>>3))*128 + o, 8 bf16 per record (c&7 fastest)
#pragma unroll
    for (int it = 0; it < 5; ++it) {
      const int idx = t + it * 256;          // 0..1151 = kk*128 + c
      if (idx < Cc * KP) {
        const int kk = idx >> 7;
        const int c = idx & 127;
        wt2[(size_t)(((b * 9 + kk) * 16 + (c >> 3)) * 128 + o) * 8 + (c & 7)] =
            wl[c * KP + kk];
      }
    }
  } else {
    const int p = (bid - (Nn * Hh + 3 * Oo)) * 256 + t;   // 0..32767
    const int n = p >> 12;
    const int rem = p & 4095;
    const int h = rem >> 6;
    const int w = rem & 63;
    const float center = depth[p];
    const float grid = center / fx[n];       // PIXEL_SIZE*DILATION = 1
    const float half = 0.5f * grid;
    unsigned int packed = 0u;
#pragma unroll
    for (int kk = 0; kk < KP; ++kk) {
      const int hh = h + kk / 3 - 1;
      const int ww = w + kk % 3 - 1;
      float d = 0.0f;
      if (hh >= 0 && hh < Hh && ww >= 0 && ww < Ww) d = depth[(n << 12) + hh * Ww + ww];
      const float valid = (d != 0.0f && center != 0.0f) ? 1.0f : 0.0f;
      const float dm = d * valid;
      unsigned int cb = 0u;
      if (fabsf(dm - (center + grid)) <= half) cb |= 1u;
      float m1v = (fabsf(dm - center) <= half) ? 1.0f : 0.0f;
      m1v = m1v + 1.0f - valid;
      if (m1v > 1.0f) m1v = 1.0f;
      if (m1v > 0.5f) cb |= 2u;
      if (fabsf(dm - (center - grid)) <= half) cb |= 4u;
      packed |= cb << (3 * kk);
    }
    codesg[p] = packed;
  }
}

#define LDXC 132          // pixel stride 264 B -> 2-way bank aliasing (free)
#define HALO_COLS 66      // w in [-1, 64]
#define HALO_ROWS 4       // h in [h0-1, h0+2]

__global__ __launch_bounds__(256, 2) void conv_main(
    const unsigned short* __restrict__ xt,
    const unsigned short* __restrict__ wt2,
    const unsigned int* __restrict__ codesg,
    float* __restrict__ out) {
  __shared__ __align__(16) unsigned short Xs[HALO_ROWS * HALO_COLS * LDXC];  // 69696 B

  const int g = blockIdx.x;          // 512 blocks
  const int n = g >> 6;
  const int rem = g & 63;
  const int pb = rem >> 1;           // 0..31  -> row pair
  const int ob1 = rem & 1;           // o-half
  const int h0 = pb * 2;

  const int tid = threadIdx.x;
  const int lane = tid & 63;
  const int wave = tid >> 6;
  const int l31 = lane & 31;
  const int lg = lane >> 5;
  const int wc = wave & 1;           // o 32-slice within the block's 64
  const int ks = wave >> 1;          // K-split: 64-c chunk

  // per-lane constant part of the B record address:
  //   rec = ((b*9+kk)*16 + ks*8 + half*4 + kc*2 + lg)*128 + (ob1*64 + wc*32 + l31)
  const unsigned short* wf =
      wt2 + ((size_t)(ks * 8 + lg) * 128 + ob1 * 64 + wc * 32 + l31) * 8;

  short8 Bb[2][6];   // double-buffered B prefetch; [kc*3+b]
  short8 Aa[2][8];   // double-buffered A prefetch; [mt*2+kc]

  // KK and HF may be runtime values (rolled loop); SLOT must be a literal.
#define LOADB(SLOT, KK, HF)                                                          \
  {                                                                                  \
    const int kkq = (KK), hfq = (HF);                                                \
    _Pragma("unroll")                                                                \
    for (int kc = 0; kc < 2; ++kc)                                                   \
      _Pragma("unroll")                                                              \
      for (int b = 0; b < 3; ++b)                                                    \
        Bb[SLOT][kc * 3 + b] = *reinterpret_cast<const short8*>(                     \
            wf + (size_t)(((b * 9 + kkq) * 16 + hfq * 4 + kc * 2)) * 1024);          \
  }

#define LOADA(SLOT, KK, HF)                                                          \
  {                                                                                  \
    const int kkp = (KK), hfp = (HF);                                                \
    const int dyp = kkp / 3, dxp = kkp - dyp * 3;                                    \
    const int pof = dyp * HALO_COLS + dxp + l31;                                     \
    _Pragma("unroll")                                                                \
    for (int mt = 0; mt < 4; ++mt)                                                   \
      _Pragma("unroll")                                                              \
      for (int kc = 0; kc < 2; ++kc) {                                               \
        const int pix = (mt >> 1) * HALO_COLS + (mt & 1) * 32 + pof;                 \
        const int coff = ks * 64 + hfp * 32 + kc * 16 + lg * 8;                      \
        Aa[SLOT][mt * 2 + kc] =                                                      \
            *reinterpret_cast<const short8*>(&Xs[pix * LDXC + coff]);                \
      }                                                                              \
  }

  // 24 MFMA on (B slot BSLOT, A slot ASLOT) at kernel tap KK.
#define COMPUTE(BSLOT, ASLOT, KK)                                                    \
  {                                                                                  \
    const int shift = 3 * (KK);                                                      \
    _Pragma("unroll")                                                                \
    for (int b = 0; b < 3; ++b) {                                                    \
      int msk[4];                                                                    \
      _Pragma("unroll")                                                              \
      for (int mt = 0; mt < 4; ++mt)                                                 \
        msk[mt] = __builtin_amdgcn_sbfe((int)cd2[mt], shift + b, 1);                 \
      _Pragma("unroll")                                                              \
      for (int kc = 0; kc < 2; ++kc) {                                               \
        _Pragma("unroll")                                                            \
        for (int mt = 0; mt < 4; ++mt) {                                             \
          intx4 a4 = *reinterpret_cast<const intx4*>(&Aa[ASLOT][mt * 2 + kc]);       \
          intx4 m4 = {msk[mt], msk[mt], msk[mt], msk[mt]};                           \
          a4 &= m4;                                                                  \
          const short8 af = *reinterpret_cast<const short8*>(&a4);                   \
          acc2[mt] = __builtin_amdgcn_mfma_f32_32x32x16_bf16(                        \
              af, Bb[BSLOT][kc * 3 + b], acc2[mt], 0, 0, 0);                         \
        }                                                                            \
      }                                                                              \
    }                                                                                \
  }

  // ---- B prologue loads FIRST: L2 latency overlaps halo staging ----
  LOADB(0, 0, 0)
  LOADB(1, 0, 1)

  // ---- branch-mask codes: lane l31 owns pixel row mt*32+l31 of the 128-pixel tile
  unsigned int cd2[4];
  {
    const unsigned int* cp = codesg + (n << 12) + h0 * 64;
#pragma unroll
    for (int mt = 0; mt < 4; ++mt) cd2[mt] = cp[mt * 32 + l31];
  }

  // ---- stage halo tile ONCE: Xs[(hrel*66 + ww+1)][c] = xt[n, h0-1+hrel, ww, c] ----
#pragma unroll
  for (int it = 0; it < 17; ++it) {
    const int idx = tid + it * 256;          // chunks of 8 channels
    if (idx < HALO_ROWS * HALO_COLS * 16) {
      const int ch = (idx & 15) << 3;
      const int pixidx = idx >> 4;           // 0..263
      const int lc = pixidx % HALO_COLS;
      const int hrel = pixidx / HALO_COLS;
      const int hh = h0 - 1 + hrel;
      const int ww = lc - 1;
      short8 v = {0, 0, 0, 0, 0, 0, 0, 0};
      if (hh >= 0 && hh < Hh && ww >= 0 && ww < Ww)
        v = *reinterpret_cast<const short8*>(
            xt + (size_t)((n * Hh + hh) * Ww + ww) * Cc + ch);
      *reinterpret_cast<short8*>(&Xs[pixidx * LDXC + ch]) = v;
    }
  }

  __syncthreads();

  f32x16 acc2[4];
#pragma unroll
  for (int mt = 0; mt < 4; ++mt)
    acc2[mt] = (f32x16){0.f, 0.f, 0.f, 0.f, 0.f, 0.f, 0.f, 0.f,
                        0.f, 0.f, 0.f, 0.f, 0.f, 0.f, 0.f, 0.f};

  LOADA(0, 0, 0)

  // ---- rolled 9-iteration K-loop, fixed 2-step double-buffered body ----
  // NO sched_group_barriers this round: single-variable A/B vs round 4.
  // (m141 precedent: order-pinning defeats the compiler's own waitcnt
  //  scheduling; this tests whether the SGB template is the ~4x invariant.)
#pragma unroll 1
  for (int p = 0; p < 8; ++p) {
    LOADA(1, p, 1)
    COMPUTE(0, 0, p)
    LOADB(0, p + 1, 0)
    LOADA(0, p + 1, 0)
    COMPUTE(1, 1, p)
    LOADB(1, p + 1, 1)
  }
  // tail p = 8
  LOADA(1, 8, 1)
  COMPUTE(0, 0, 8)
  COMPUTE(1, 1, 8)

  // ---- split-K reduction: ks=1 waves dump partials into LDS (Xs is dead) ----
  __syncthreads();
  float* scratch = reinterpret_cast<float*>(Xs);   // 32 KB used of 69.7 KB
  if (ks == 1) {
#pragma unroll
    for (int mt = 0; mt < 4; ++mt)
#pragma unroll
      for (int q4 = 0; q4 < 4; ++q4) {
        const floatx4 v = {acc2[mt][q4 * 4 + 0], acc2[mt][q4 * 4 + 1],
                           acc2[mt][q4 * 4 + 2], acc2[mt][q4 * 4 + 3]};
        *reinterpret_cast<floatx4*>(
            &scratch[(((wc * 4 + mt) * 4 + q4) * 64 + lane) * 4]) = v;
      }
  }
  __syncthreads();
  if (ks == 0) {
    const int o = ob1 * 64 + wc * 32 + l31;
#pragma unroll
    for (int mt = 0; mt < 4; ++mt) {
      const int h = h0 + (mt >> 1);
      const int wbase = (mt & 1) * 32;
#pragma unroll
      for (int q4 = 0; q4 < 4; ++q4) {
        const floatx4 other = *reinterpret_cast<const floatx4*>(
            &scratch[(((wc * 4 + mt) * 4 + q4) * 64 + lane) * 4]);
        const floatx4 mine = {acc2[mt][q4 * 4 + 0], acc2[mt][q4 * 4 + 1],
                              acc2[mt][q4 * 4 + 2], acc2[mt][q4 * 4 + 3]};
        const floatx4 sum = mine + other;
        const int w = wbase + q4 * 8 + lg * 4;   // row=(reg&3)+8*(reg>>2)+4*lg
        float* dst = out + (size_t)(n * Oo + o) * LL + h * Ww + w;
        *reinterpret_cast<floatx4*>(dst) = sum;
      }
    }
  }
}

extern "C" void kernel_launch(void* const* d_in, const int* in_sizes, int n_in,
                              void* d_out, int out_size, void* d_ws, size_t ws_size,
                              hipStream_t stream) {
  const float* x     = (const float*)d_in[0];
  const float* depth = (const float*)d_in[1];
  const float* fx    = (const float*)d_in[2];
  const float* w0    = (const float*)d_in[3];
  const float* w1    = (const float*)d_in[4];
  const float* w2    = (const float*)d_in[5];
  float* out = (float*)d_out;

  // ws layout: xt (8 MB) | wt2 (0.88 MB) | codes (128 KB)
  unsigned short* xt = (unsigned short*)d_ws;
  unsigned short* wt2 = xt + (size_t)Nn * Hh * Ww * Cc;
  unsigned int* codesg = (unsigned int*)(wt2 + (size_t)3 * KP * Oo * Cc);

  prep_all<<<Nn * Hh + 3 * Oo + 128, 256, 0, stream>>>(x, w0, w1, w2, depth, fx, xt, wt2, codesg);
  conv_main<<<512, 256, 0, stream>>>(xt, wt2, codesg, out);
}